// Round 3
// baseline (907.850 us; speedup 1.0000x reference)
//
#include <hip/hip_runtime.h>

typedef unsigned int u32;

// B=65536, D=256, H=512, C=10, P=10, HP=128. fp32 tensors; rdd int32.
// 32 rows/block, 512 threads (8 waves). Fully fused:
//  - xs staged k-major (pad 36) -> conflict-free writes, broadcast b128 reads
//  - layer1: wave owns 4 rows x 512 cols (8 cols/lane); Wt1 redundancy served by L1
//  - layer2 fused in regs, butterfly reduce -> fp32 logits (bitmap must match fp32 ref)
//  - top-2 bitmap -> per-patch row lists -> grouped patch passes (8 rows/pass)
//    so Wp1[p] streams ~once per block instead of once per (row,patch).

__global__ __launch_bounds__(512) void netsum_kernel(
    const float* __restrict__ x,   const float* __restrict__ Wt1, const float* __restrict__ bt1,
    const float* __restrict__ Wt2, const float* __restrict__ bt2,
    const float* __restrict__ Wp1, const float* __restrict__ bp1,
    const float* __restrict__ Wp2, const float* __restrict__ bp2,
    const int* __restrict__ rdd, float* __restrict__ out)
{
    __shared__ float xs[256][36];   // x^T tile: xs[k][row], padded 32->36
    __shared__ float lg[32][10];    // logits incl bt2
    __shared__ float oacc[32][10];  // gated patch accumulation
    __shared__ u32 bmp[32];
    __shared__ u32 plist[10][32];   // rows per patch
    __shared__ u32 pcnt[10];
    __shared__ int rdds[20];

    const int t = threadIdx.x;
    const int lane = t & 63;
    const int w = t >> 6;             // wave 0..7
    const int row0 = blockIdx.x * 32;

    if (t < 10) pcnt[t] = 0;
    if (t < 20) rdds[t] = rdd[t];
    if (t < 320) ((float*)oacc)[t] = 0.f;

    // ---- stage x transposed: thread t -> row t&31, k block (t>>5)*16 ----
    {
        const int ki = t >> 5, row = t & 31;
        const float* src = x + (size_t)(row0 + row) * 256 + ki * 16;
        #pragma unroll
        for (int j = 0; j < 16; j += 4) {
            float4 v = *(const float4*)(src + j);
            xs[ki*16 + j + 0][row] = v.x;
            xs[ki*16 + j + 1][row] = v.y;
            xs[ki*16 + j + 2][row] = v.z;
            xs[ki*16 + j + 3][row] = v.w;
        }
    }
    __syncthreads();

    // ---- layer 1 (4 rows/wave, 8 cols/lane) + fused layer 2 ----
    {
        float acc[4][8];
        #pragma unroll
        for (int r = 0; r < 4; ++r)
            #pragma unroll
            for (int j = 0; j < 8; ++j) acc[r][j] = 0.f;

        const int col0 = lane * 8;
        const float* wp = Wt1 + col0;
        for (int k = 0; k < 256; ++k) {
            float4 wa = *(const float4*)(wp + (size_t)k * 512);
            float4 wb = *(const float4*)(wp + (size_t)k * 512 + 4);
            float4 xv = *(const float4*)&xs[k][w * 4];   // wave-uniform broadcast
            const float wf[8] = {wa.x, wa.y, wa.z, wa.w, wb.x, wb.y, wb.z, wb.w};
            const float xr[4] = {xv.x, xv.y, xv.z, xv.w};
            #pragma unroll
            for (int r = 0; r < 4; ++r)
                #pragma unroll
                for (int j = 0; j < 8; ++j) acc[r][j] += xr[r] * wf[j];
        }

        float4 b0 = *(const float4*)(bt1 + col0);
        float4 b1 = *(const float4*)(bt1 + col0 + 4);
        const float bb[8] = {b0.x, b0.y, b0.z, b0.w, b1.x, b1.y, b1.z, b1.w};

        float lp[4][10];
        #pragma unroll
        for (int r = 0; r < 4; ++r)
            #pragma unroll
            for (int c = 0; c < 10; ++c) lp[r][c] = 0.f;

        #pragma unroll
        for (int j = 0; j < 8; ++j) {
            const float* w2 = Wt2 + (size_t)(col0 + j) * 10;
            float wv[10];
            #pragma unroll
            for (int c = 0; c < 10; ++c) wv[c] = w2[c];
            float hr[4];
            #pragma unroll
            for (int r = 0; r < 4; ++r) {
                float h = acc[r][j] + bb[j];
                hr[r] = h > 0.f ? h : 0.f;
            }
            #pragma unroll
            for (int r = 0; r < 4; ++r)
                #pragma unroll
                for (int c = 0; c < 10; ++c) lp[r][c] += hr[r] * wv[c];
        }

        // reduce each row's 10 partial logits across the wave
        #pragma unroll
        for (int r = 0; r < 4; ++r) {
            #pragma unroll
            for (int c = 0; c < 10; ++c) {
                float v = lp[r][c];
                #pragma unroll
                for (int off = 32; off > 0; off >>= 1) v += __shfl_xor(v, off, 64);
                lp[r][c] = v;
            }
            if (lane < 10) lg[w*4 + r][lane] = lp[r][lane] + bt2[lane];
        }
    }
    __syncthreads();

    // ---- top-2 bitmap + per-patch row lists (threads 0..31) ----
    if (t < 32) {
        float best = -1e30f; int i0 = 0;
        #pragma unroll
        for (int c = 0; c < 10; ++c) { float v = lg[t][c]; if (v > best) { best = v; i0 = c; } }
        float b2 = -1e30f; int i1 = 0;
        #pragma unroll
        for (int c = 0; c < 10; ++c) { if (c == i0) continue; float v = lg[t][c]; if (v > b2) { b2 = v; i1 = c; } }
        u32 exact = 0, fb = 0;
        #pragma unroll
        for (int p = 0; p < 10; ++p) {
            int a = rdds[2*p], b = rdds[2*p+1];
            if (i0 == a && i1 == b) exact |= 1u << p;
            if (i0 == a)            fb    |= 1u << p;
        }
        u32 bits = exact ? exact : fb;
        bmp[t] = bits;
        while (bits) {
            int p = __ffs(bits) - 1;
            bits &= bits - 1;
            u32 idx = atomicAdd(&pcnt[p], 1u);
            plist[p][idx] = (u32)t;
        }
    }
    __syncthreads();

    // ---- grouped patch passes: one patch at a time, 8 rows (one/wave) per pass ----
    {
        const int pc0 = lane * 2;
        for (int p = 0; p < 10; ++p) {
            const int L = (int)pcnt[p];
            for (int base = 0; base < L; base += 8) {
                const int ridx = base + w;          // wave-uniform
                if (ridx < L) {
                    const int row = (int)plist[p][ridx];
                    const float* wb1 = Wp1 + (size_t)p * 32768 + pc0;
                    float h0 = 0.f, h1 = 0.f;
                    #pragma unroll 4
                    for (int k = 0; k < 256; ++k) {
                        float2 wv = *(const float2*)(wb1 + (size_t)k * 128);
                        float xv = xs[k][row];       // wave-uniform broadcast
                        h0 += xv * wv.x;
                        h1 += xv * wv.y;
                    }
                    float2 bv = *(const float2*)(bp1 + p * 128 + pc0);
                    h0 += bv.x; h1 += bv.y;
                    h0 = h0 > 0.f ? h0 : 0.f;
                    h1 = h1 > 0.f ? h1 : 0.f;
                    const float* w2 = Wp2 + (size_t)p * 1280 + (size_t)pc0 * 10;
                    float p2[10];
                    #pragma unroll
                    for (int c = 0; c < 10; ++c) p2[c] = h0 * w2[c] + h1 * w2[10 + c];
                    #pragma unroll
                    for (int c = 0; c < 10; ++c) {
                        float v = p2[c];
                        #pragma unroll
                        for (int off = 32; off > 0; off >>= 1) v += __shfl_xor(v, off, 64);
                        p2[c] = v;
                    }
                    if (lane < 10)
                        atomicAdd(&oacc[row][lane], p2[lane] + bp2[p * 10 + lane]);
                }
            }
        }
    }
    __syncthreads();

    // ---- output: out = logits + gated patch sums ----
    if (t < 320) {
        out[(size_t)row0 * 10 + t] = ((const float*)lg)[t] + ((const float*)oacc)[t];
    }
}

extern "C" void kernel_launch(void* const* d_in, const int* in_sizes, int n_in,
                              void* d_out, int out_size, void* d_ws, size_t ws_size,
                              hipStream_t stream) {
    const float* x   = (const float*)d_in[0];
    const float* Wt1 = (const float*)d_in[1];
    const float* bt1 = (const float*)d_in[2];
    const float* Wt2 = (const float*)d_in[3];
    const float* bt2 = (const float*)d_in[4];
    const float* Wp1 = (const float*)d_in[5];
    const float* bp1 = (const float*)d_in[6];
    const float* Wp2 = (const float*)d_in[7];
    const float* bp2 = (const float*)d_in[8];
    const int* rdd = (const int*)d_in[9];
    float* out = (float*)d_out;

    dim3 grid(65536 / 32), block(512);
    hipLaunchKernelGGL(netsum_kernel, grid, block, 0, stream,
                       x, Wt1, bt1, Wt2, bt2, Wp1, bp1, Wp2, bp2, rdd, out);
}

// Round 4
// 476.314 us; speedup vs baseline: 1.9060x; 1.9060x over previous
//
#include <hip/hip_runtime.h>

typedef unsigned int u32;
typedef unsigned short u16;
typedef __attribute__((ext_vector_type(8))) short bf16x8;
typedef __attribute__((ext_vector_type(4))) float f32x4;

#define MARGIN 1e-3f

__device__ __forceinline__ u16 bf16rn(float f){
    u32 u = __float_as_uint(f);
    return (u16)((u + 0x7fffu + ((u >> 16) & 1u)) >> 16);
}
__device__ __forceinline__ float bfup(u16 h){ return __uint_as_float(((u32)h) << 16); }

// ---- pre-pass: Wt1 fp32[256][512] -> hi/lo bf16 transposed [512][256];
//      Wp1 fp32[10][256][128] -> hi bf16 transposed [10][128][256] ----
__global__ __launch_bounds__(256) void conv_kernel(
    const float* __restrict__ Wt1, const float* __restrict__ Wp1,
    u16* __restrict__ wt1hi, u16* __restrict__ wt1lo, u16* __restrict__ wp1hi)
{
    int i = blockIdx.x * 256 + threadIdx.x;
    if (i < 131072) {
        int n = i >> 8, k = i & 255;
        float f = Wt1[k * 512 + n];
        u16 h = bf16rn(f);
        wt1hi[i] = h;
        wt1lo[i] = bf16rn(f - bfup(h));
    } else if (i < 458752) {
        int j = i - 131072;
        int p = j >> 15, r = j & 32767, n = r >> 8, k = r & 255;
        wp1hi[j] = bf16rn(Wp1[p * 32768 + k * 128 + n]);
    }
}

__global__ __launch_bounds__(512) void netsum_kernel(
    const float* __restrict__ x,   const float* __restrict__ Wt1, const float* __restrict__ bt1,
    const float* __restrict__ Wt2, const float* __restrict__ bt2,
    const float* __restrict__ bp1, const float* __restrict__ Wp2, const float* __restrict__ bp2,
    const int* __restrict__ rdd,
    const u16* __restrict__ wt1hi, const u16* __restrict__ wt1lo, const u16* __restrict__ wp1hi,
    float* __restrict__ out)
{
    __shared__ u16 xhi[64][264];    // x rows, bf16 hi (pad 256->264: 528B row stride)
    __shared__ u16 xlo[64][264];    // bf16 residual
    __shared__ float wt2s[512][10];
    __shared__ float bt1s[512];
    __shared__ float bt2s[10];
    __shared__ float lg[64][10];    // logits (init bt2, atomicAdd partials)
    __shared__ float oacc[64][10];  // gated patch sums
    __shared__ u32 plist[10][64];
    __shared__ u32 pcnt[10];
    __shared__ int rdds[20];
    __shared__ u32 elist[64];
    __shared__ u32 ecnt;
    __shared__ u32 wq[40];
    __shared__ u32 nwork;

    const int t = threadIdx.x;
    const int lane = t & 63;
    const int w = t >> 6;          // 8 waves
    const int ln = lane & 15;
    const int quad = lane >> 4;
    const int row0 = blockIdx.x * 64;

    if (t < 10) { pcnt[t] = 0; bt2s[t] = bt2[t]; }
    if (t < 20) rdds[t] = rdd[t];
    if (t == 0) { ecnt = 0; nwork = 0; }
    for (int i = t; i < 640; i += 512) {
        ((float*)lg)[i] = bt2[i % 10];
        ((float*)oacc)[i] = 0.f;
    }
    for (int i = t; i < 5120; i += 512) ((float*)wt2s)[i] = Wt2[i];
    bt1s[t & 511] = bt1[t & 511];

    // ---- stage x -> bf16 hi/lo in LDS ----
    {
        const int r = t >> 3, k0 = (t & 7) * 32;
        const float* src = x + (size_t)(row0 + r) * 256 + k0;
        #pragma unroll
        for (int j = 0; j < 32; j += 2) {
            float f0 = src[j], f1 = src[j + 1];
            u16 h0 = bf16rn(f0), h1 = bf16rn(f1);
            u16 l0 = bf16rn(f0 - bfup(h0)), l1 = bf16rn(f1 - bfup(h1));
            *(u32*)&xhi[r][k0 + j] = (u32)h0 | ((u32)h1 << 16);
            *(u32*)&xlo[r][k0 + j] = (u32)l0 | ((u32)l1 << 16);
        }
    }
    __syncthreads();

    // ---- layer 1 split-bf16 MFMA + fused fp32 layer 2 ----
    {
        float lp[4][10];
        #pragma unroll
        for (int r2 = 0; r2 < 4; ++r2)
            #pragma unroll
            for (int c = 0; c < 10; ++c) lp[r2][c] = 0.f;

        const int mtile = w & 3;            // 4 m-tiles of 16 rows
        const int ntbase = (w >> 2) * 16;   // 2 n-halves of 16 tiles
        const u16* xh_row = &xhi[mtile * 16 + ln][0];
        const u16* xl_row = &xlo[mtile * 16 + ln][0];

        for (int g = 0; g < 4; ++g) {       // 4 groups of 4 n-tiles
            f32x4 acc[4] = {{0.f,0.f,0.f,0.f},{0.f,0.f,0.f,0.f},
                            {0.f,0.f,0.f,0.f},{0.f,0.f,0.f,0.f}};
            const int nt0 = ntbase + g * 4;
            for (int kk = 0; kk < 8; ++kk) {
                const int ko = kk * 32 + quad * 8;
                bf16x8 ah = *(const bf16x8*)(xh_row + ko);
                bf16x8 al = *(const bf16x8*)(xl_row + ko);
                #pragma unroll
                for (int i2 = 0; i2 < 4; ++i2) {
                    const int n = (nt0 + i2) * 16 + ln;
                    bf16x8 bh = *(const bf16x8*)(wt1hi + n * 256 + ko);
                    bf16x8 bl = *(const bf16x8*)(wt1lo + n * 256 + ko);
                    acc[i2] = __builtin_amdgcn_mfma_f32_16x16x32_bf16(ah, bh, acc[i2], 0, 0, 0);
                    acc[i2] = __builtin_amdgcn_mfma_f32_16x16x32_bf16(ah, bl, acc[i2], 0, 0, 0);
                    acc[i2] = __builtin_amdgcn_mfma_f32_16x16x32_bf16(al, bh, acc[i2], 0, 0, 0);
                }
            }
            #pragma unroll
            for (int i2 = 0; i2 < 4; ++i2) {
                const int n = (nt0 + i2) * 16 + ln;
                const float bias = bt1s[n];
                float wv[10];
                #pragma unroll
                for (int c = 0; c < 10; ++c) wv[c] = wt2s[n][c];
                float h0 = acc[i2].x + bias; h0 = h0 > 0.f ? h0 : 0.f;
                float h1 = acc[i2].y + bias; h1 = h1 > 0.f ? h1 : 0.f;
                float h2 = acc[i2].z + bias; h2 = h2 > 0.f ? h2 : 0.f;
                float h3 = acc[i2].w + bias; h3 = h3 > 0.f ? h3 : 0.f;
                #pragma unroll
                for (int c = 0; c < 10; ++c) {
                    lp[0][c] += h0 * wv[c];
                    lp[1][c] += h1 * wv[c];
                    lp[2][c] += h2 * wv[c];
                    lp[3][c] += h3 * wv[c];
                }
            }
        }
        // reduce over the 16 col-lanes; quad leader commits (static indices only)
        #pragma unroll
        for (int r2 = 0; r2 < 4; ++r2)
            #pragma unroll
            for (int c = 0; c < 10; ++c) {
                float v = lp[r2][c];
                v += __shfl_xor(v, 1, 64); v += __shfl_xor(v, 2, 64);
                v += __shfl_xor(v, 4, 64); v += __shfl_xor(v, 8, 64);
                lp[r2][c] = v;
            }
        if (ln == 0) {
            const int m = mtile * 16 + quad * 4;
            #pragma unroll
            for (int r2 = 0; r2 < 4; ++r2)
                #pragma unroll
                for (int c = 0; c < 10; ++c)
                    atomicAdd(&lg[m + r2][c], lp[r2][c]);
        }
    }
    __syncthreads();

    // ---- margin check: rows with tight top-2 decision -> exact recompute list ----
    if (t < 64) {
        float l[10];
        #pragma unroll
        for (int c = 0; c < 10; ++c) l[c] = lg[t][c];
        float b0 = -1e30f; int i0 = 0;
        #pragma unroll
        for (int c = 0; c < 10; ++c) if (l[c] > b0) { b0 = l[c]; i0 = c; }
        float b1 = -1e30f; int i1 = 0;
        #pragma unroll
        for (int c = 0; c < 10; ++c) { if (c == i0) continue; if (l[c] > b1) { b1 = l[c]; i1 = c; } }
        float b2v = -1e30f;
        #pragma unroll
        for (int c = 0; c < 10; ++c) { if (c == i0 || c == i1) continue; if (l[c] > b2v) b2v = l[c]; }
        if (b0 - b1 < MARGIN || b1 - b2v < MARGIN) {
            u32 e = atomicAdd(&ecnt, 1u);
            elist[e] = (u32)t;
        }
    }
    __syncthreads();

    // ---- exact fp32 recompute for flagged rows (one wave per row) ----
    {
        const u32 ec = ecnt;
        for (u32 ii = w; ii < ec; ii += 8) {
            const int row = (int)elist[ii];
            const float* xr = x + (size_t)(row0 + row) * 256;
            const int n0 = lane * 8;
            float ha[8];
            #pragma unroll
            for (int j = 0; j < 8; ++j) ha[j] = 0.f;
            for (int k = 0; k < 256; ++k) {
                float xv = xr[k];
                float4 wa = *(const float4*)(Wt1 + (size_t)k * 512 + n0);
                float4 wb = *(const float4*)(Wt1 + (size_t)k * 512 + n0 + 4);
                ha[0] += xv * wa.x; ha[1] += xv * wa.y; ha[2] += xv * wa.z; ha[3] += xv * wa.w;
                ha[4] += xv * wb.x; ha[5] += xv * wb.y; ha[6] += xv * wb.z; ha[7] += xv * wb.w;
            }
            float l10[10];
            #pragma unroll
            for (int c = 0; c < 10; ++c) l10[c] = 0.f;
            #pragma unroll
            for (int j = 0; j < 8; ++j) {
                float h = ha[j] + bt1s[n0 + j]; h = h > 0.f ? h : 0.f;
                #pragma unroll
                for (int c = 0; c < 10; ++c) l10[c] += h * wt2s[n0 + j][c];
            }
            #pragma unroll
            for (int c = 0; c < 10; ++c) {
                float v = l10[c];
                v += __shfl_xor(v, 1, 64);  v += __shfl_xor(v, 2, 64);
                v += __shfl_xor(v, 4, 64);  v += __shfl_xor(v, 8, 64);
                v += __shfl_xor(v, 16, 64); v += __shfl_xor(v, 32, 64);
                l10[c] = v;
            }
            if (lane == 0) {
                #pragma unroll
                for (int c = 0; c < 10; ++c) lg[row][c] = l10[c] + bt2s[c];
            }
        }
    }
    __syncthreads();

    // ---- bitmap + per-patch row lists ----
    if (t < 64) {
        float l[10];
        #pragma unroll
        for (int c = 0; c < 10; ++c) l[c] = lg[t][c];
        float b0 = -1e30f; int i0 = 0;
        #pragma unroll
        for (int c = 0; c < 10; ++c) if (l[c] > b0) { b0 = l[c]; i0 = c; }
        float b1 = -1e30f; int i1 = 0;
        #pragma unroll
        for (int c = 0; c < 10; ++c) { if (c == i0) continue; if (l[c] > b1) { b1 = l[c]; i1 = c; } }
        u32 exact = 0, fb = 0;
        #pragma unroll
        for (int p = 0; p < 10; ++p) {
            int a = rdds[2 * p], b = rdds[2 * p + 1];
            if (i0 == a && i1 == b) exact |= 1u << p;
            if (i0 == a)            fb    |= 1u << p;
        }
        u32 bits = exact ? exact : fb;
        while (bits) {
            int p = __ffs(bits) - 1;
            bits &= bits - 1;
            u32 idx = atomicAdd(&pcnt[p], 1u);
            plist[p][idx] = (u32)t;
        }
    }
    __syncthreads();
    if (t < 10) {
        int L = (int)pcnt[t];
        for (int base = 0; base < L; base += 16) {
            u32 e = atomicAdd(&nwork, 1u);
            wq[e] = ((u32)t << 8) | (u32)base;
        }
    }
    __syncthreads();

    // ---- gated patch nets: bf16 MFMA on gathered 16-row tiles ----
    {
        const u32 nw = nwork;
        for (u32 ii = w; ii < nw; ii += 8) {
            const u32 item = wq[ii];
            const int p = (int)(item >> 8), mbase = (int)(item & 255);
            const int Lp = (int)pcnt[p];
            const int mi = mbase + ln;
            const int arow = (mi < Lp) ? (int)plist[p][mi] : (int)plist[p][0];
            const u16* xr = &xhi[arow][0];
            const u16* wb0 = wp1hi + p * 32768;
            float pl[4][10];
            #pragma unroll
            for (int r2 = 0; r2 < 4; ++r2)
                #pragma unroll
                for (int c = 0; c < 10; ++c) pl[r2][c] = 0.f;

            #pragma unroll
            for (int g = 0; g < 2; ++g) {
                f32x4 acc[4] = {{0.f,0.f,0.f,0.f},{0.f,0.f,0.f,0.f},
                                {0.f,0.f,0.f,0.f},{0.f,0.f,0.f,0.f}};
                for (int kk = 0; kk < 8; ++kk) {
                    const int ko = kk * 32 + quad * 8;
                    bf16x8 a = *(const bf16x8*)(xr + ko);
                    #pragma unroll
                    for (int i2 = 0; i2 < 4; ++i2) {
                        const int n = (g * 4 + i2) * 16 + ln;
                        bf16x8 b = *(const bf16x8*)(wb0 + n * 256 + ko);
                        acc[i2] = __builtin_amdgcn_mfma_f32_16x16x32_bf16(a, b, acc[i2], 0, 0, 0);
                    }
                }
                #pragma unroll
                for (int i2 = 0; i2 < 4; ++i2) {
                    const int n = (g * 4 + i2) * 16 + ln;
                    const float bias = bp1[p * 128 + n];
                    const float* w2 = Wp2 + p * 1280 + n * 10;
                    float wv[10];
                    #pragma unroll
                    for (int c = 0; c < 10; ++c) wv[c] = w2[c];
                    float h0 = acc[i2].x + bias; h0 = h0 > 0.f ? h0 : 0.f;
                    float h1 = acc[i2].y + bias; h1 = h1 > 0.f ? h1 : 0.f;
                    float h2 = acc[i2].z + bias; h2 = h2 > 0.f ? h2 : 0.f;
                    float h3 = acc[i2].w + bias; h3 = h3 > 0.f ? h3 : 0.f;
                    #pragma unroll
                    for (int c = 0; c < 10; ++c) {
                        pl[0][c] += h0 * wv[c];
                        pl[1][c] += h1 * wv[c];
                        pl[2][c] += h2 * wv[c];
                        pl[3][c] += h3 * wv[c];
                    }
                }
            }
            #pragma unroll
            for (int r2 = 0; r2 < 4; ++r2)
                #pragma unroll
                for (int c = 0; c < 10; ++c) {
                    float v = pl[r2][c];
                    v += __shfl_xor(v, 1, 64); v += __shfl_xor(v, 2, 64);
                    v += __shfl_xor(v, 4, 64); v += __shfl_xor(v, 8, 64);
                    pl[r2][c] = v;
                }
            if (ln == 0) {
                #pragma unroll
                for (int r2 = 0; r2 < 4; ++r2) {
                    const int mi2 = mbase + quad * 4 + r2;
                    if (mi2 < Lp) {
                        const int row = (int)plist[p][mi2];
                        #pragma unroll
                        for (int c = 0; c < 10; ++c)
                            atomicAdd(&oacc[row][c], pl[r2][c] + bp2[p * 10 + c]);
                    }
                }
            }
        }
    }
    __syncthreads();

    for (int i = t; i < 640; i += 512)
        out[(size_t)row0 * 10 + i] = ((float*)lg)[i] + ((float*)oacc)[i];
}

extern "C" void kernel_launch(void* const* d_in, const int* in_sizes, int n_in,
                              void* d_out, int out_size, void* d_ws, size_t ws_size,
                              hipStream_t stream) {
    const float* x   = (const float*)d_in[0];
    const float* Wt1 = (const float*)d_in[1];
    const float* bt1 = (const float*)d_in[2];
    const float* Wt2 = (const float*)d_in[3];
    const float* bt2 = (const float*)d_in[4];
    const float* Wp1 = (const float*)d_in[5];
    const float* bp1 = (const float*)d_in[6];
    const float* Wp2 = (const float*)d_in[7];
    const float* bp2 = (const float*)d_in[8];
    const int* rdd = (const int*)d_in[9];
    float* out = (float*)d_out;

    u16* wt1hi = (u16*)d_ws;              // 131072 u16
    u16* wt1lo = wt1hi + 131072;          // 131072 u16
    u16* wp1hi = wt1lo + 131072;          // 327680 u16  (total ~1.15 MB)

    hipLaunchKernelGGL(conv_kernel, dim3(1792), dim3(256), 0, stream,
                       Wt1, Wp1, wt1hi, wt1lo, wp1hi);
    hipLaunchKernelGGL(netsum_kernel, dim3(1024), dim3(512), 0, stream,
                       x, Wt1, bt1, Wt2, bt2, bp1, Wp2, bp2, rdd,
                       wt1hi, wt1lo, wp1hi, out);
}

// Round 5
// 463.777 us; speedup vs baseline: 1.9575x; 1.0270x over previous
//
#include <hip/hip_runtime.h>

typedef unsigned int u32;
typedef unsigned short u16;
typedef __attribute__((ext_vector_type(8))) short bf16x8;
typedef __attribute__((ext_vector_type(4))) float f32x4;

#define MARGIN 1e-3f

__device__ __forceinline__ u16 bf16rn(float f){
    u32 u = __float_as_uint(f);
    return (u16)((u + 0x7fffu + ((u >> 16) & 1u)) >> 16);
}
__device__ __forceinline__ float bfup(u16 h){ return __uint_as_float(((u32)h) << 16); }

// ---- pre-pass (coalesced reads, scattered writes):
//  Wt1 fp32[256][512] -> hi/lo bf16 transposed [512][256]
//  Wp1 fp32[10][256][128] -> hi bf16 transposed [10][128][256]
__global__ __launch_bounds__(256) void conv_kernel(
    const float* __restrict__ Wt1, const float* __restrict__ Wp1,
    u16* __restrict__ wt1hi, u16* __restrict__ wt1lo, u16* __restrict__ wp1hi)
{
    int i = blockIdx.x * 256 + threadIdx.x;
    if (i < 131072) {
        int k = i >> 9, n = i & 511;          // read coalesced over n
        float f = Wt1[i];
        u16 h = bf16rn(f);
        wt1hi[n * 256 + k] = h;
        wt1lo[n * 256 + k] = bf16rn(f - bfup(h));
    } else if (i < 458752) {
        int j = i - 131072;
        int p = j >> 15, r = j & 32767, k = r >> 7, n = r & 127;
        wp1hi[p * 32768 + n * 256 + k] = bf16rn(Wp1[j]);
    }
}

__global__ __launch_bounds__(512, 4) void netsum_kernel(
    const float* __restrict__ x,   const float* __restrict__ Wt1, const float* __restrict__ bt1,
    const float* __restrict__ Wt2, const float* __restrict__ bt2,
    const float* __restrict__ bp1, const float* __restrict__ Wp2, const float* __restrict__ bp2,
    const int* __restrict__ rdd,
    const u16* __restrict__ wt1hi, const u16* __restrict__ wt1lo, const u16* __restrict__ wp1hi,
    float* __restrict__ out)
{
    __shared__ u16 xhi[64][264];    // 33.8 KB (528B row stride: 16B-aligned, 2-way LDS alias = free)
    __shared__ u16 xlo[64][264];    // 33.8 KB
    __shared__ float lg[64][10];    // logits (init bt2, atomicAdd partials)
    __shared__ float oacc[64][10];  // gated patch sums
    __shared__ u32 plist[10][64];
    __shared__ u32 pcnt[10];
    __shared__ int rdds[20];
    __shared__ u32 elist[64];
    __shared__ u32 ecnt;
    __shared__ u32 wq[40];
    __shared__ u32 nwork;
    // total ~76 KB -> 2 blocks/CU

    const int t = threadIdx.x;
    const int lane = t & 63;
    const int w = t >> 6;          // 8 waves
    const int ln = lane & 15;
    const int quad = lane >> 4;
    const int row0 = blockIdx.x * 64;

    if (t < 10) pcnt[t] = 0;
    if (t < 20) rdds[t] = rdd[t];
    if (t == 0) { ecnt = 0; nwork = 0; }
    for (int i = t; i < 640; i += 512) {
        ((float*)lg)[i] = bt2[i % 10];
        ((float*)oacc)[i] = 0.f;
    }

    // ---- stage x -> bf16 hi/lo in LDS ----
    {
        const int r = t >> 3, k0 = (t & 7) * 32;
        const float* src = x + (size_t)(row0 + r) * 256 + k0;
        #pragma unroll
        for (int j = 0; j < 32; j += 2) {
            float f0 = src[j], f1 = src[j + 1];
            u16 h0 = bf16rn(f0), h1 = bf16rn(f1);
            u16 l0 = bf16rn(f0 - bfup(h0)), l1 = bf16rn(f1 - bfup(h1));
            *(u32*)&xhi[r][k0 + j] = (u32)h0 | ((u32)h1 << 16);
            *(u32*)&xlo[r][k0 + j] = (u32)l0 | ((u32)l1 << 16);
        }
    }
    __syncthreads();

    // ---- layer 1 split-bf16 MFMA + fused fp32 layer 2 ----
    // waves: 2 m-groups (32 rows) x 4 n-groups (8 n-tiles, in 2 passes of 4)
    {
        const int mg = w & 1;
        const int ng = w >> 1;
        const u16* xh0 = &xhi[mg * 32 + ln][0];
        const u16* xl0 = &xlo[mg * 32 + ln][0];
        const u16* xh1 = &xhi[mg * 32 + 16 + ln][0];
        const u16* xl1 = &xlo[mg * 32 + 16 + ln][0];

        #pragma unroll
        for (int g = 0; g < 2; ++g) {
            f32x4 acc[2][4];
            #pragma unroll
            for (int m = 0; m < 2; ++m)
                #pragma unroll
                for (int i2 = 0; i2 < 4; ++i2) acc[m][i2] = (f32x4){0.f,0.f,0.f,0.f};

            const int nt0 = (ng * 8 + g * 4) * 16 + ln;   // n for i2=0
            for (int kk = 0; kk < 8; ++kk) {
                const int ko = kk * 32 + quad * 8;
                bf16x8 ah0 = *(const bf16x8*)(xh0 + ko);
                bf16x8 al0 = *(const bf16x8*)(xl0 + ko);
                bf16x8 ah1 = *(const bf16x8*)(xh1 + ko);
                bf16x8 al1 = *(const bf16x8*)(xl1 + ko);
                #pragma unroll
                for (int i2 = 0; i2 < 4; ++i2) {
                    const int n = nt0 + i2 * 16;
                    bf16x8 bh = *(const bf16x8*)(wt1hi + n * 256 + ko);
                    bf16x8 bl = *(const bf16x8*)(wt1lo + n * 256 + ko);
                    acc[0][i2] = __builtin_amdgcn_mfma_f32_16x16x32_bf16(ah0, bh, acc[0][i2], 0, 0, 0);
                    acc[0][i2] = __builtin_amdgcn_mfma_f32_16x16x32_bf16(ah0, bl, acc[0][i2], 0, 0, 0);
                    acc[0][i2] = __builtin_amdgcn_mfma_f32_16x16x32_bf16(al0, bh, acc[0][i2], 0, 0, 0);
                    acc[1][i2] = __builtin_amdgcn_mfma_f32_16x16x32_bf16(ah1, bh, acc[1][i2], 0, 0, 0);
                    acc[1][i2] = __builtin_amdgcn_mfma_f32_16x16x32_bf16(ah1, bl, acc[1][i2], 0, 0, 0);
                    acc[1][i2] = __builtin_amdgcn_mfma_f32_16x16x32_bf16(al1, bh, acc[1][i2], 0, 0, 0);
                }
            }
            // epilogue: relu + Wt2, committed per (g, m) to keep registers low
            #pragma unroll
            for (int m = 0; m < 2; ++m) {
                float lp[4][10];
                #pragma unroll
                for (int r2 = 0; r2 < 4; ++r2)
                    #pragma unroll
                    for (int c = 0; c < 10; ++c) lp[r2][c] = 0.f;
                #pragma unroll
                for (int i2 = 0; i2 < 4; ++i2) {
                    const int n = nt0 + i2 * 16;
                    const float bias = bt1[n];
                    const float* w2 = Wt2 + n * 10;
                    float wv[10];
                    #pragma unroll
                    for (int c = 0; c < 10; ++c) wv[c] = w2[c];
                    float h0 = acc[m][i2].x + bias; h0 = h0 > 0.f ? h0 : 0.f;
                    float h1 = acc[m][i2].y + bias; h1 = h1 > 0.f ? h1 : 0.f;
                    float h2 = acc[m][i2].z + bias; h2 = h2 > 0.f ? h2 : 0.f;
                    float h3 = acc[m][i2].w + bias; h3 = h3 > 0.f ? h3 : 0.f;
                    #pragma unroll
                    for (int c = 0; c < 10; ++c) {
                        lp[0][c] += h0 * wv[c];
                        lp[1][c] += h1 * wv[c];
                        lp[2][c] += h2 * wv[c];
                        lp[3][c] += h3 * wv[c];
                    }
                }
                #pragma unroll
                for (int r2 = 0; r2 < 4; ++r2)
                    #pragma unroll
                    for (int c = 0; c < 10; ++c) {
                        float v = lp[r2][c];
                        v += __shfl_xor(v, 1, 64); v += __shfl_xor(v, 2, 64);
                        v += __shfl_xor(v, 4, 64); v += __shfl_xor(v, 8, 64);
                        lp[r2][c] = v;
                    }
                if (ln == 0) {
                    const int mrow = mg * 32 + m * 16 + quad * 4;
                    #pragma unroll
                    for (int r2 = 0; r2 < 4; ++r2)
                        #pragma unroll
                        for (int c = 0; c < 10; ++c)
                            atomicAdd(&lg[mrow + r2][c], lp[r2][c]);
                }
            }
        }
    }
    __syncthreads();

    // ---- margin check -> exact recompute list ----
    if (t < 64) {
        float l[10];
        #pragma unroll
        for (int c = 0; c < 10; ++c) l[c] = lg[t][c];
        float b0 = -1e30f; int i0 = 0;
        #pragma unroll
        for (int c = 0; c < 10; ++c) if (l[c] > b0) { b0 = l[c]; i0 = c; }
        float b1 = -1e30f; int i1 = 0;
        #pragma unroll
        for (int c = 0; c < 10; ++c) { if (c == i0) continue; if (l[c] > b1) { b1 = l[c]; i1 = c; } }
        float b2v = -1e30f;
        #pragma unroll
        for (int c = 0; c < 10; ++c) { if (c == i0 || c == i1) continue; if (l[c] > b2v) b2v = l[c]; }
        if (b0 - b1 < MARGIN || b1 - b2v < MARGIN) {
            u32 e = atomicAdd(&ecnt, 1u);
            elist[e] = (u32)t;
        }
    }
    __syncthreads();

    // ---- exact fp32 recompute for flagged rows (one wave per row) ----
    {
        const u32 ec = ecnt;
        for (u32 ii = w; ii < ec; ii += 8) {
            const int row = (int)elist[ii];
            const float* xr = x + (size_t)(row0 + row) * 256;
            const int n0 = lane * 8;
            float ha[8];
            #pragma unroll
            for (int j = 0; j < 8; ++j) ha[j] = 0.f;
            for (int k = 0; k < 256; ++k) {
                float xv = xr[k];
                float4 wa = *(const float4*)(Wt1 + (size_t)k * 512 + n0);
                float4 wb = *(const float4*)(Wt1 + (size_t)k * 512 + n0 + 4);
                ha[0] += xv * wa.x; ha[1] += xv * wa.y; ha[2] += xv * wa.z; ha[3] += xv * wa.w;
                ha[4] += xv * wb.x; ha[5] += xv * wb.y; ha[6] += xv * wb.z; ha[7] += xv * wb.w;
            }
            float l10[10];
            #pragma unroll
            for (int c = 0; c < 10; ++c) l10[c] = 0.f;
            #pragma unroll
            for (int j = 0; j < 8; ++j) {
                float h = ha[j] + bt1[n0 + j]; h = h > 0.f ? h : 0.f;
                const float* w2 = Wt2 + (n0 + j) * 10;
                #pragma unroll
                for (int c = 0; c < 10; ++c) l10[c] += h * w2[c];
            }
            #pragma unroll
            for (int c = 0; c < 10; ++c) {
                float v = l10[c];
                v += __shfl_xor(v, 1, 64);  v += __shfl_xor(v, 2, 64);
                v += __shfl_xor(v, 4, 64);  v += __shfl_xor(v, 8, 64);
                v += __shfl_xor(v, 16, 64); v += __shfl_xor(v, 32, 64);
                l10[c] = v;
            }
            if (lane == 0) {
                #pragma unroll
                for (int c = 0; c < 10; ++c) lg[row][c] = l10[c] + bt2[c];
            }
        }
    }
    __syncthreads();

    // ---- bitmap + per-patch row lists ----
    if (t < 64) {
        float l[10];
        #pragma unroll
        for (int c = 0; c < 10; ++c) l[c] = lg[t][c];
        float b0 = -1e30f; int i0 = 0;
        #pragma unroll
        for (int c = 0; c < 10; ++c) if (l[c] > b0) { b0 = l[c]; i0 = c; }
        float b1 = -1e30f; int i1 = 0;
        #pragma unroll
        for (int c = 0; c < 10; ++c) { if (c == i0) continue; if (l[c] > b1) { b1 = l[c]; i1 = c; } }
        u32 exact = 0, fb = 0;
        #pragma unroll
        for (int p = 0; p < 10; ++p) {
            int a = rdds[2 * p], b = rdds[2 * p + 1];
            if (i0 == a && i1 == b) exact |= 1u << p;
            if (i0 == a)            fb    |= 1u << p;
        }
        u32 bits = exact ? exact : fb;
        while (bits) {
            int p = __ffs(bits) - 1;
            bits &= bits - 1;
            u32 idx = atomicAdd(&pcnt[p], 1u);
            plist[p][idx] = (u32)t;
        }
    }
    __syncthreads();
    if (t < 10) {
        int L = (int)pcnt[t];
        for (int base = 0; base < L; base += 16) {
            u32 e = atomicAdd(&nwork, 1u);
            wq[e] = ((u32)t << 8) | (u32)base;
        }
    }
    __syncthreads();

    // ---- gated patch nets: bf16 MFMA on gathered 16-row tiles ----
    {
        const u32 nw = nwork;
        for (u32 ii = w; ii < nw; ii += 8) {
            const u32 item = wq[ii];
            const int p = (int)(item >> 8), mbase = (int)(item & 255);
            const int Lp = (int)pcnt[p];
            const int mi = mbase + ln;
            const int arow = (mi < Lp) ? (int)plist[p][mi] : (int)plist[p][0];
            const u16* xr = &xhi[arow][0];
            const u16* wb0 = wp1hi + p * 32768;
            float pl[4][10];
            #pragma unroll
            for (int r2 = 0; r2 < 4; ++r2)
                #pragma unroll
                for (int c = 0; c < 10; ++c) pl[r2][c] = 0.f;

            #pragma unroll
            for (int g = 0; g < 2; ++g) {
                f32x4 acc[4];
                #pragma unroll
                for (int i2 = 0; i2 < 4; ++i2) acc[i2] = (f32x4){0.f,0.f,0.f,0.f};
                for (int kk = 0; kk < 8; ++kk) {
                    const int ko = kk * 32 + quad * 8;
                    bf16x8 a = *(const bf16x8*)(xr + ko);
                    #pragma unroll
                    for (int i2 = 0; i2 < 4; ++i2) {
                        const int n = (g * 4 + i2) * 16 + ln;
                        bf16x8 b = *(const bf16x8*)(wb0 + n * 256 + ko);
                        acc[i2] = __builtin_amdgcn_mfma_f32_16x16x32_bf16(a, b, acc[i2], 0, 0, 0);
                    }
                }
                #pragma unroll
                for (int i2 = 0; i2 < 4; ++i2) {
                    const int n = (g * 4 + i2) * 16 + ln;
                    const float bias = bp1[p * 128 + n];
                    const float* w2 = Wp2 + p * 1280 + n * 10;
                    float wv[10];
                    #pragma unroll
                    for (int c = 0; c < 10; ++c) wv[c] = w2[c];
                    float h0 = acc[i2].x + bias; h0 = h0 > 0.f ? h0 : 0.f;
                    float h1 = acc[i2].y + bias; h1 = h1 > 0.f ? h1 : 0.f;
                    float h2 = acc[i2].z + bias; h2 = h2 > 0.f ? h2 : 0.f;
                    float h3 = acc[i2].w + bias; h3 = h3 > 0.f ? h3 : 0.f;
                    #pragma unroll
                    for (int c = 0; c < 10; ++c) {
                        pl[0][c] += h0 * wv[c];
                        pl[1][c] += h1 * wv[c];
                        pl[2][c] += h2 * wv[c];
                        pl[3][c] += h3 * wv[c];
                    }
                }
            }
            #pragma unroll
            for (int r2 = 0; r2 < 4; ++r2)
                #pragma unroll
                for (int c = 0; c < 10; ++c) {
                    float v = pl[r2][c];
                    v += __shfl_xor(v, 1, 64); v += __shfl_xor(v, 2, 64);
                    v += __shfl_xor(v, 4, 64); v += __shfl_xor(v, 8, 64);
                    pl[r2][c] = v;
                }
            if (ln == 0) {
                #pragma unroll
                for (int r2 = 0; r2 < 4; ++r2) {
                    const int mi2 = mbase + quad * 4 + r2;
                    if (mi2 < Lp) {
                        const int row = (int)plist[p][mi2];
                        #pragma unroll
                        for (int c = 0; c < 10; ++c)
                            atomicAdd(&oacc[row][c], pl[r2][c] + bp2[p * 10 + c]);
                    }
                }
            }
        }
    }
    __syncthreads();

    for (int i = t; i < 640; i += 512)
        out[(size_t)row0 * 10 + i] = ((float*)lg)[i] + ((float*)oacc)[i];
}

extern "C" void kernel_launch(void* const* d_in, const int* in_sizes, int n_in,
                              void* d_out, int out_size, void* d_ws, size_t ws_size,
                              hipStream_t stream) {
    const float* x   = (const float*)d_in[0];
    const float* Wt1 = (const float*)d_in[1];
    const float* bt1 = (const float*)d_in[2];
    const float* Wt2 = (const float*)d_in[3];
    const float* bt2 = (const float*)d_in[4];
    const float* Wp1 = (const float*)d_in[5];
    const float* bp1 = (const float*)d_in[6];
    const float* Wp2 = (const float*)d_in[7];
    const float* bp2 = (const float*)d_in[8];
    const int* rdd = (const int*)d_in[9];
    float* out = (float*)d_out;

    u16* wt1hi = (u16*)d_ws;              // 131072 u16
    u16* wt1lo = wt1hi + 131072;          // 131072 u16
    u16* wp1hi = wt1lo + 131072;          // 327680 u16

    hipLaunchKernelGGL(conv_kernel, dim3(1792), dim3(256), 0, stream,
                       Wt1, Wp1, wt1hi, wt1lo, wp1hi);
    hipLaunchKernelGGL(netsum_kernel, dim3(1024), dim3(512), 0, stream,
                       x, Wt1, bt1, Wt2, bt2, bp1, Wp2, bp2, rdd,
                       wt1hi, wt1lo, wp1hi, out);
}

// Round 6
// 417.258 us; speedup vs baseline: 2.1758x; 1.1115x over previous
//
#include <hip/hip_runtime.h>

typedef unsigned int u32;
typedef unsigned short u16;
typedef __attribute__((ext_vector_type(8))) short bf16x8;
typedef __attribute__((ext_vector_type(4))) float f32x4;

#define MARGIN 1e-3f

__device__ __forceinline__ u16 bf16rn(float f){
    u32 u = __float_as_uint(f);
    return (u16)((u + 0x7fffu + ((u >> 16) & 1u)) >> 16);
}
__device__ __forceinline__ float bfup(u16 h){ return __uint_as_float(((u32)h) << 16); }

// ---- pre-pass: LDS-tiled transpose+convert, coalesced both sides ----
// blocks 0..31:   Wt1 fp32[256][512] -> wt1hi/lo bf16 [512][256]   (4 k-tiles x 8 n-tiles)
// blocks 32..111: Wp1 fp32[10][256][128] -> wp1hi bf16 [10][128][256] (per p: 4 k x 2 n)
// block 112:      Wt2 [512][10] -> wt2t fp32 [10][512]; Wp2 [10][128][10] -> wp2t [10][10][128]
__global__ __launch_bounds__(256) void conv_kernel(
    const float* __restrict__ Wt1, const float* __restrict__ Wp1,
    const float* __restrict__ Wt2, const float* __restrict__ Wp2,
    u16* __restrict__ wt1hi, u16* __restrict__ wt1lo, u16* __restrict__ wp1hi,
    float* __restrict__ wt2t, float* __restrict__ wp2t)
{
    __shared__ float tile[64][68];
    const int t = threadIdx.x;
    const int b = blockIdx.x;

    if (b == 112) {
        for (int i = t; i < 5120; i += 256) {
            int n = i / 10, c = i % 10;
            wt2t[c * 512 + n] = Wt2[i];
        }
        for (int i = t; i < 12800; i += 256) {
            int p = i / 1280, r = i % 1280, n = r / 10, c = r % 10;
            wp2t[p * 1280 + c * 128 + n] = Wp2[i];
        }
        return;
    }

    const float* src; int src_ld, kt, nt;
    u16 *dhi, *dlo;
    if (b < 32) {
        kt = b & 3; nt = b >> 2;
        src = Wt1 + (size_t)(kt * 64) * 512 + nt * 64; src_ld = 512;
        dhi = wt1hi + (size_t)(nt * 64) * 256 + kt * 64;
        dlo = wt1lo + (size_t)(nt * 64) * 256 + kt * 64;
    } else {
        int j = b - 32, p = j >> 3, r = j & 7;
        kt = r & 3; nt = r >> 2;
        src = Wp1 + (size_t)p * 32768 + (size_t)(kt * 64) * 128 + nt * 64; src_ld = 128;
        dhi = wp1hi + (size_t)p * 32768 + (size_t)(nt * 64) * 256 + kt * 64;
        dlo = nullptr;
    }
    {
        const int kr = t >> 2, c0 = (t & 3) * 16;
        #pragma unroll
        for (int u = 0; u < 4; ++u) {
            float4 v = *(const float4*)(src + (size_t)kr * src_ld + c0 + u * 4);
            tile[kr][c0 + u*4 + 0] = v.x;
            tile[kr][c0 + u*4 + 1] = v.y;
            tile[kr][c0 + u*4 + 2] = v.z;
            tile[kr][c0 + u*4 + 3] = v.w;
        }
    }
    __syncthreads();
    {
        const int nr = t >> 2, k0 = (t & 3) * 16;
        u16 hv[16], lv[16];
        #pragma unroll
        for (int j = 0; j < 16; ++j) {
            float f = tile[k0 + j][nr];
            hv[j] = bf16rn(f);
            lv[j] = bf16rn(f - bfup(hv[j]));
        }
        #pragma unroll
        for (int j = 0; j < 16; ++j) dhi[(size_t)nr * 256 + k0 + j] = hv[j];
        if (dlo)
            #pragma unroll
            for (int j = 0; j < 16; ++j) dlo[(size_t)nr * 256 + k0 + j] = lv[j];
    }
}

__global__ __launch_bounds__(512, 2) void netsum_kernel(
    const float* __restrict__ x,   const float* __restrict__ Wt1, const float* __restrict__ bt1,
    const float* __restrict__ bt2,
    const float* __restrict__ bp1, const float* __restrict__ bp2,
    const int* __restrict__ rdd,
    const u16* __restrict__ wt1hi, const u16* __restrict__ wt1lo, const u16* __restrict__ wp1hi,
    const float* __restrict__ wt2t, const float* __restrict__ wp2t,
    float* __restrict__ out)
{
    __shared__ u16 xhi[64][264];    // 33.8 KB (528B row stride)
    __shared__ u16 xlo[64][264];    // 33.8 KB
    __shared__ float lg[64][10];
    __shared__ float oacc[64][10];
    __shared__ u32 plist[10][64];
    __shared__ u32 pcnt[10];
    __shared__ int rdds[20];
    __shared__ u32 elist[64];
    __shared__ u32 ecnt;
    __shared__ u32 wq[40];
    __shared__ u32 nwork;
    // ~76 KB -> 2 blocks/CU

    const int t = threadIdx.x;
    const int lane = t & 63;
    const int w = t >> 6;
    const int ln = lane & 15;
    const int quad = lane >> 4;
    const int row0 = blockIdx.x * 64;

    if (t < 10) pcnt[t] = 0;
    if (t < 20) rdds[t] = rdd[t];
    if (t == 0) { ecnt = 0; nwork = 0; }
    for (int i = t; i < 640; i += 512) {
        ((float*)lg)[i] = bt2[i % 10];
        ((float*)oacc)[i] = 0.f;
    }

    // ---- stage x -> bf16 hi/lo in LDS (coalesced: wave fills one row per op) ----
    {
        #pragma unroll
        for (int i = 0; i < 8; ++i) {
            int f = t + 512 * i;           // float4 index 0..4095
            int r = f >> 6, c4 = f & 63;
            float4 v = *(const float4*)(x + (size_t)(row0 + r) * 256 + c4 * 4);
            u16 h0 = bf16rn(v.x), h1 = bf16rn(v.y), h2 = bf16rn(v.z), h3 = bf16rn(v.w);
            u16 l0 = bf16rn(v.x - bfup(h0)), l1 = bf16rn(v.y - bfup(h1));
            u16 l2 = bf16rn(v.z - bfup(h2)), l3 = bf16rn(v.w - bfup(h3));
            uint2 hw = { (u32)h0 | ((u32)h1 << 16), (u32)h2 | ((u32)h3 << 16) };
            uint2 lw = { (u32)l0 | ((u32)l1 << 16), (u32)l2 | ((u32)l3 << 16) };
            *(uint2*)&xhi[r][c4 * 4] = hw;
            *(uint2*)&xlo[r][c4 * 4] = lw;
        }
    }
    __syncthreads();

    // ---- layer 1 split-bf16 MFMA + fused fp32 layer 2 ----
    {
        const int mg = w & 1;
        const int ng = w >> 1;
        const u16* xh0 = &xhi[mg * 32 + ln][0];
        const u16* xl0 = &xlo[mg * 32 + ln][0];
        const u16* xh1 = &xhi[mg * 32 + 16 + ln][0];
        const u16* xl1 = &xlo[mg * 32 + 16 + ln][0];

        #pragma unroll
        for (int g = 0; g < 2; ++g) {
            f32x4 acc[2][4];
            #pragma unroll
            for (int m = 0; m < 2; ++m)
                #pragma unroll
                for (int i2 = 0; i2 < 4; ++i2) acc[m][i2] = (f32x4){0.f,0.f,0.f,0.f};

            const int nt0 = (ng * 8 + g * 4) * 16 + ln;
            for (int kk = 0; kk < 8; ++kk) {
                const int ko = kk * 32 + quad * 8;
                bf16x8 ah0 = *(const bf16x8*)(xh0 + ko);
                bf16x8 al0 = *(const bf16x8*)(xl0 + ko);
                bf16x8 ah1 = *(const bf16x8*)(xh1 + ko);
                bf16x8 al1 = *(const bf16x8*)(xl1 + ko);
                #pragma unroll
                for (int i2 = 0; i2 < 4; ++i2) {
                    const int n = nt0 + i2 * 16;
                    bf16x8 bh = *(const bf16x8*)(wt1hi + n * 256 + ko);
                    bf16x8 bl = *(const bf16x8*)(wt1lo + n * 256 + ko);
                    acc[0][i2] = __builtin_amdgcn_mfma_f32_16x16x32_bf16(ah0, bh, acc[0][i2], 0, 0, 0);
                    acc[0][i2] = __builtin_amdgcn_mfma_f32_16x16x32_bf16(ah0, bl, acc[0][i2], 0, 0, 0);
                    acc[0][i2] = __builtin_amdgcn_mfma_f32_16x16x32_bf16(al0, bh, acc[0][i2], 0, 0, 0);
                    acc[1][i2] = __builtin_amdgcn_mfma_f32_16x16x32_bf16(ah1, bh, acc[1][i2], 0, 0, 0);
                    acc[1][i2] = __builtin_amdgcn_mfma_f32_16x16x32_bf16(ah1, bl, acc[1][i2], 0, 0, 0);
                    acc[1][i2] = __builtin_amdgcn_mfma_f32_16x16x32_bf16(al1, bh, acc[1][i2], 0, 0, 0);
                }
            }
            #pragma unroll
            for (int m = 0; m < 2; ++m) {
                float lp[4][10];
                #pragma unroll
                for (int r2 = 0; r2 < 4; ++r2)
                    #pragma unroll
                    for (int c = 0; c < 10; ++c) lp[r2][c] = 0.f;
                #pragma unroll
                for (int i2 = 0; i2 < 4; ++i2) {
                    const int n = nt0 + i2 * 16;
                    const float bias = bt1[n];
                    float wv[10];
                    #pragma unroll
                    for (int c = 0; c < 10; ++c) wv[c] = wt2t[c * 512 + n];  // coalesced
                    float h0 = acc[m][i2].x + bias; h0 = h0 > 0.f ? h0 : 0.f;
                    float h1 = acc[m][i2].y + bias; h1 = h1 > 0.f ? h1 : 0.f;
                    float h2 = acc[m][i2].z + bias; h2 = h2 > 0.f ? h2 : 0.f;
                    float h3 = acc[m][i2].w + bias; h3 = h3 > 0.f ? h3 : 0.f;
                    #pragma unroll
                    for (int c = 0; c < 10; ++c) {
                        lp[0][c] += h0 * wv[c];
                        lp[1][c] += h1 * wv[c];
                        lp[2][c] += h2 * wv[c];
                        lp[3][c] += h3 * wv[c];
                    }
                }
                #pragma unroll
                for (int r2 = 0; r2 < 4; ++r2)
                    #pragma unroll
                    for (int c = 0; c < 10; ++c) {
                        float v = lp[r2][c];
                        v += __shfl_xor(v, 1, 64); v += __shfl_xor(v, 2, 64);
                        v += __shfl_xor(v, 4, 64); v += __shfl_xor(v, 8, 64);
                        lp[r2][c] = v;
                    }
                if (ln == 0) {
                    const int mrow = mg * 32 + m * 16 + quad * 4;
                    #pragma unroll
                    for (int r2 = 0; r2 < 4; ++r2)
                        #pragma unroll
                        for (int c = 0; c < 10; ++c)
                            atomicAdd(&lg[mrow + r2][c], lp[r2][c]);
                }
            }
        }
    }
    __syncthreads();

    // ---- margin check -> exact recompute list ----
    if (t < 64) {
        float l[10];
        #pragma unroll
        for (int c = 0; c < 10; ++c) l[c] = lg[t][c];
        float b0 = -1e30f; int i0 = 0;
        #pragma unroll
        for (int c = 0; c < 10; ++c) if (l[c] > b0) { b0 = l[c]; i0 = c; }
        float b1 = -1e30f; int i1 = 0;
        #pragma unroll
        for (int c = 0; c < 10; ++c) { if (c == i0) continue; if (l[c] > b1) { b1 = l[c]; i1 = c; } }
        float b2v = -1e30f;
        #pragma unroll
        for (int c = 0; c < 10; ++c) { if (c == i0 || c == i1) continue; if (l[c] > b2v) b2v = l[c]; }
        if (b0 - b1 < MARGIN || b1 - b2v < MARGIN) {
            u32 e = atomicAdd(&ecnt, 1u);
            elist[e] = (u32)t;
        }
    }
    __syncthreads();

    // ---- exact fp32 recompute for flagged rows ----
    {
        const u32 ec = ecnt;
        for (u32 ii = w; ii < ec; ii += 8) {
            const int row = (int)elist[ii];
            const float* xr = x + (size_t)(row0 + row) * 256;
            const int n0 = lane * 8;
            float ha[8];
            #pragma unroll
            for (int j = 0; j < 8; ++j) ha[j] = 0.f;
            for (int k = 0; k < 256; ++k) {
                float xv = xr[k];
                float4 wa = *(const float4*)(Wt1 + (size_t)k * 512 + n0);
                float4 wb = *(const float4*)(Wt1 + (size_t)k * 512 + n0 + 4);
                ha[0] += xv * wa.x; ha[1] += xv * wa.y; ha[2] += xv * wa.z; ha[3] += xv * wa.w;
                ha[4] += xv * wb.x; ha[5] += xv * wb.y; ha[6] += xv * wb.z; ha[7] += xv * wb.w;
            }
            float l10[10];
            #pragma unroll
            for (int c = 0; c < 10; ++c) l10[c] = 0.f;
            #pragma unroll
            for (int j = 0; j < 8; ++j) {
                float h = ha[j] + bt1[n0 + j]; h = h > 0.f ? h : 0.f;
                #pragma unroll
                for (int c = 0; c < 10; ++c) l10[c] += h * wt2t[c * 512 + n0 + j];
            }
            #pragma unroll
            for (int c = 0; c < 10; ++c) {
                float v = l10[c];
                v += __shfl_xor(v, 1, 64);  v += __shfl_xor(v, 2, 64);
                v += __shfl_xor(v, 4, 64);  v += __shfl_xor(v, 8, 64);
                v += __shfl_xor(v, 16, 64); v += __shfl_xor(v, 32, 64);
                l10[c] = v;
            }
            if (lane == 0) {
                #pragma unroll
                for (int c = 0; c < 10; ++c) lg[row][c] = l10[c] + bt2[c];
            }
        }
    }
    __syncthreads();

    // ---- bitmap + per-patch row lists ----
    if (t < 64) {
        float l[10];
        #pragma unroll
        for (int c = 0; c < 10; ++c) l[c] = lg[t][c];
        float b0 = -1e30f; int i0 = 0;
        #pragma unroll
        for (int c = 0; c < 10; ++c) if (l[c] > b0) { b0 = l[c]; i0 = c; }
        float b1 = -1e30f; int i1 = 0;
        #pragma unroll
        for (int c = 0; c < 10; ++c) { if (c == i0) continue; if (l[c] > b1) { b1 = l[c]; i1 = c; } }
        u32 exact = 0, fb = 0;
        #pragma unroll
        for (int p = 0; p < 10; ++p) {
            int a = rdds[2 * p], b = rdds[2 * p + 1];
            if (i0 == a && i1 == b) exact |= 1u << p;
            if (i0 == a)            fb    |= 1u << p;
        }
        u32 bits = exact ? exact : fb;
        while (bits) {
            int p = __ffs(bits) - 1;
            bits &= bits - 1;
            u32 idx = atomicAdd(&pcnt[p], 1u);
            plist[p][idx] = (u32)t;
        }
    }
    __syncthreads();
    if (t < 10) {
        int L = (int)pcnt[t];
        for (int base = 0; base < L; base += 16) {
            u32 e = atomicAdd(&nwork, 1u);
            wq[e] = ((u32)t << 8) | (u32)base;
        }
    }
    __syncthreads();

    // ---- gated patch nets: bf16 MFMA on gathered 16-row tiles ----
    {
        const u32 nw = nwork;
        for (u32 ii = w; ii < nw; ii += 8) {
            const u32 item = wq[ii];
            const int p = (int)(item >> 8), mbase = (int)(item & 255);
            const int Lp = (int)pcnt[p];
            const int mi = mbase + ln;
            const int arow = (mi < Lp) ? (int)plist[p][mi] : (int)plist[p][0];
            const u16* xr = &xhi[arow][0];
            const u16* wb0 = wp1hi + p * 32768;
            float pl[4][10];
            #pragma unroll
            for (int r2 = 0; r2 < 4; ++r2)
                #pragma unroll
                for (int c = 0; c < 10; ++c) pl[r2][c] = 0.f;

            #pragma unroll
            for (int g = 0; g < 2; ++g) {
                f32x4 acc[4];
                #pragma unroll
                for (int i2 = 0; i2 < 4; ++i2) acc[i2] = (f32x4){0.f,0.f,0.f,0.f};
                for (int kk = 0; kk < 8; ++kk) {
                    const int ko = kk * 32 + quad * 8;
                    bf16x8 a = *(const bf16x8*)(xr + ko);
                    #pragma unroll
                    for (int i2 = 0; i2 < 4; ++i2) {
                        const int n = (g * 4 + i2) * 16 + ln;
                        bf16x8 b = *(const bf16x8*)(wb0 + n * 256 + ko);
                        acc[i2] = __builtin_amdgcn_mfma_f32_16x16x32_bf16(a, b, acc[i2], 0, 0, 0);
                    }
                }
                #pragma unroll
                for (int i2 = 0; i2 < 4; ++i2) {
                    const int n = (g * 4 + i2) * 16 + ln;
                    const float bias = bp1[p * 128 + n];
                    float wv[10];
                    #pragma unroll
                    for (int c = 0; c < 10; ++c) wv[c] = wp2t[p * 1280 + c * 128 + n];  // coalesced
                    float h0 = acc[i2].x + bias; h0 = h0 > 0.f ? h0 : 0.f;
                    float h1 = acc[i2].y + bias; h1 = h1 > 0.f ? h1 : 0.f;
                    float h2 = acc[i2].z + bias; h2 = h2 > 0.f ? h2 : 0.f;
                    float h3 = acc[i2].w + bias; h3 = h3 > 0.f ? h3 : 0.f;
                    #pragma unroll
                    for (int c = 0; c < 10; ++c) {
                        pl[0][c] += h0 * wv[c];
                        pl[1][c] += h1 * wv[c];
                        pl[2][c] += h2 * wv[c];
                        pl[3][c] += h3 * wv[c];
                    }
                }
            }
            #pragma unroll
            for (int r2 = 0; r2 < 4; ++r2)
                #pragma unroll
                for (int c = 0; c < 10; ++c) {
                    float v = pl[r2][c];
                    v += __shfl_xor(v, 1, 64); v += __shfl_xor(v, 2, 64);
                    v += __shfl_xor(v, 4, 64); v += __shfl_xor(v, 8, 64);
                    pl[r2][c] = v;
                }
            if (ln == 0) {
                #pragma unroll
                for (int r2 = 0; r2 < 4; ++r2) {
                    const int mi2 = mbase + quad * 4 + r2;
                    if (mi2 < Lp) {
                        const int row = (int)plist[p][mi2];
                        #pragma unroll
                        for (int c = 0; c < 10; ++c)
                            atomicAdd(&oacc[row][c], pl[r2][c] + bp2[p * 10 + c]);
                    }
                }
            }
        }
    }
    __syncthreads();

    for (int i = t; i < 640; i += 512)
        out[(size_t)row0 * 10 + i] = ((float*)lg)[i] + ((float*)oacc)[i];
}

extern "C" void kernel_launch(void* const* d_in, const int* in_sizes, int n_in,
                              void* d_out, int out_size, void* d_ws, size_t ws_size,
                              hipStream_t stream) {
    const float* x   = (const float*)d_in[0];
    const float* Wt1 = (const float*)d_in[1];
    const float* bt1 = (const float*)d_in[2];
    const float* Wt2 = (const float*)d_in[3];
    const float* bt2 = (const float*)d_in[4];
    const float* Wp1 = (const float*)d_in[5];
    const float* bp1 = (const float*)d_in[6];
    const float* Wp2 = (const float*)d_in[7];
    const float* bp2 = (const float*)d_in[8];
    const int* rdd = (const int*)d_in[9];
    float* out = (float*)d_out;

    u16* wt1hi = (u16*)d_ws;              // 131072 u16
    u16* wt1lo = wt1hi + 131072;          // 131072 u16
    u16* wp1hi = wt1lo + 131072;          // 327680 u16
    float* wt2t = (float*)(wp1hi + 327680);   // 5120 f32
    float* wp2t = wt2t + 5120;                // 12800 f32

    hipLaunchKernelGGL(conv_kernel, dim3(113), dim3(256), 0, stream,
                       Wt1, Wp1, Wt2, Wp2, wt1hi, wt1lo, wp1hi, wt2t, wp2t);
    hipLaunchKernelGGL(netsum_kernel, dim3(1024), dim3(512), 0, stream,
                       x, Wt1, bt1, bt2, bp1, bp2, rdd,
                       wt1hi, wt1lo, wp1hi, wt2t, wp2t, out);
}